// Round 1
// 1499.892 us; speedup vs baseline: 1.1558x; 1.1558x over previous
//
#include <hip/hip_runtime.h>
#include <stdint.h>

// LSTM autoencoder: B=256,T=256,D=128,H=256, gate order i,f,g,o.
// Phases: cvt/perm prep -> enc xproj GEMM -> enc recurrence (persistent, batch-sliced)
//         -> dec xproj GEMM -> dec recurrence.
// R1: recurrence — full on-chip weight residency (regs+LDS), double-buffered h,
//     1 barrier/step, xp added post-MFMA, global stores after barrier.
// R2: fixed k_permW/k_permB gate stride for 8-wave dec.
// R3: xp latency elimination. xproj now writes xpE/xpD pre-swizzled per (t,wg,wave) as
//     [chunk i=gq>>1][lq][b][h2*4+j] so a wave's whole-step xp = NCH coalesced 512B
//     dwordx4 loads into uint4 xq[NCH] (32 VGPRs enc). Chunks are reloaded IN PLACE for
//     t+1 right after their last consumer (even chunks after q1, odd after q3) ->
//     ~1500-2500 cyc lead, all global latency hidden, no extra buffering.
//     Also: v_cvt_pk_bf16_f32 for bf16 packing (1 instr vs ~10), Bh loads unconditional
//     (cols 8-15 garbage never read; in-LDS-bounds; 2-way bank alias = free), enc h
//     re-read from LDS post-barrier instead of hsv regs (-8 VGPR).

#define B_N 256
#define T_N 256
#define D_N 128
#define H_N 256

typedef __attribute__((ext_vector_type(8))) short bf16x8;  // MFMA A/B frag (4 VGPRs)
typedef __attribute__((ext_vector_type(4))) float f32x4;   // MFMA C/D frag
typedef unsigned short u16;
typedef unsigned int u32;

__device__ __forceinline__ float bflo(u32 u){ return __uint_as_float(u << 16); }
__device__ __forceinline__ float bfhi(u32 u){ return __uint_as_float(u & 0xffff0000u); }
__device__ __forceinline__ u32 f2bf_bits(float f){ u32 u = __float_as_uint(f); return (u + 0x7fffu + ((u >> 16) & 1u)) >> 16; }
__device__ __forceinline__ u32 pack2(float lo, float hi){ return f2bf_bits(lo) | (f2bf_bits(hi) << 16); }
__device__ __forceinline__ u32 cvtpk(float lo, float hi){ u32 r; asm("v_cvt_pk_bf16_f32 %0, %1, %2" : "=v"(r) : "v"(lo), "v"(hi)); return r; }
__device__ __forceinline__ float sigm(float x){ return __builtin_amdgcn_rcpf(1.f + __expf(-x)); }
__device__ __forceinline__ float tanh_f(float x){ return 1.f - 2.f * __builtin_amdgcn_rcpf(1.f + __expf(2.f * x)); }
__device__ __forceinline__ float xpj(uint2 r, int j){
  return j == 0 ? bflo(r.x) : j == 1 ? bfhi(r.x) : j == 2 ? bflo(r.y) : bfhi(r.y);
}

// ---------- prep kernels ----------
__global__ void k_cvt(const float* __restrict__ src, u16* __restrict__ dst, int n){
  int i = (blockIdx.x * blockDim.x + threadIdx.x) * 4;
  if (i >= n) return;
  float4 v = *(const float4*)(src + i);
  uint2 o; o.x = pack2(v.x, v.y); o.y = pack2(v.z, v.w);
  *(uint2*)(dst + i) = o;
}

// Row permutation p -> orig so that wave v (of 1<<VB waves) owns rows
// [v*4U,(v+1)*4U) = {i,f,g,o} x units[v*U,(v+1)*U), U = 1<<UB units/wave.
// p = (v << (UB+2)) | (g << UB) | uo  ;  orig = (g << (UB+VB)) | (v << UB) | uo
__global__ void k_permW(const float* __restrict__ W, u16* __restrict__ Wp, int K, int UB, int VB){
  int p = blockIdx.x;
  int uo = p & ((1 << UB) - 1), g = (p >> UB) & 3, v = p >> (UB + 2);
  int orig = (g << (UB + VB)) | (v << UB) | uo;
  for (int k = threadIdx.x; k < K; k += blockDim.x)
    Wp[(size_t)p * K + k] = (u16)f2bf_bits(W[(size_t)orig * K + k]);
}

__global__ void k_permB(const float* __restrict__ b1, const float* __restrict__ b2,
                        float* __restrict__ bp, int P, int UB, int VB){
  for (int p = threadIdx.x; p < P; p += blockDim.x){
    int uo = p & ((1 << UB) - 1), g = (p >> UB) & 3, v = p >> (UB + 2);
    int orig = (g << (UB + VB)) | (v << UB) | uo;
    bp[p] = b1[orig] + b2[orig];
  }
}

// ---------- input-projection GEMM: out[m,n] = sum_k A[m,k]*W[n,k] + bias[n] ----------
// Output layout (consumed by k_rec): u16 index =
//   t*TS + (b>>3)*WS + wv*VS + (gq>>1)*256 + (u>>2)*64 + (b&7)*8 + (gq&1)*4 + (u&3)
// where n=p decomposes as wv=p>>(UB+2), g=(p>>UB)&3, q=(p&((1<<UB)-1))>>4, u=p&15,
// gq=g*NQ+q. This makes a rec-wave's per-step xp NCH contiguous 512B chunks.
template<int KTOT, bool ENC_MAP, int UB, int VB>
__global__ __launch_bounds__(256, 1) void k_xproj(const u16* __restrict__ A, const u16* __restrict__ W,
                                                  const float* __restrict__ bias, u16* __restrict__ outp){
  constexpr int NQ  = 1 << (UB - 4);
  constexpr int NCH = 2 * NQ;
  constexpr size_t VS = (size_t)NCH * 256;
  constexpr size_t WS = (size_t)(1 << VB) * VS;
  constexpr size_t TS = 32 * WS;
  __shared__ u16 As[64][72];
  __shared__ u16 Ws[64][72];
  const int tid = threadIdx.x, l = tid & 63, v = tid >> 6;
  const int lb = l & 15, lq = l >> 4;
  const int m0 = blockIdx.x * 64, n0 = blockIdx.y * 64;
  f32x4 acc[4];
#pragma unroll
  for (int nt = 0; nt < 4; nt++){ float bv = bias[n0 + nt * 16 + lb]; f32x4 t = {bv, bv, bv, bv}; acc[nt] = t; }
  const int r = tid >> 3, c8 = (tid & 7) * 8;
  for (int kb = 0; kb < KTOT / 64; ++kb){
    __syncthreads();
    *(bf16x8*)&As[r][c8]      = *(const bf16x8*)&A[(size_t)(m0 + r) * KTOT + kb * 64 + c8];
    *(bf16x8*)&As[r + 32][c8] = *(const bf16x8*)&A[(size_t)(m0 + r + 32) * KTOT + kb * 64 + c8];
    *(bf16x8*)&Ws[r][c8]      = *(const bf16x8*)&W[(size_t)(n0 + r) * KTOT + kb * 64 + c8];
    *(bf16x8*)&Ws[r + 32][c8] = *(const bf16x8*)&W[(size_t)(n0 + r + 32) * KTOT + kb * 64 + c8];
    __syncthreads();
#pragma unroll
    for (int kc = 0; kc < 2; kc++){
      bf16x8 af = *(const bf16x8*)&As[v * 16 + lb][kc * 32 + lq * 8];
#pragma unroll
      for (int nt = 0; nt < 4; nt++){
        bf16x8 wf = *(const bf16x8*)&Ws[nt * 16 + lb][kc * 32 + lq * 8];
        acc[nt] = __builtin_amdgcn_mfma_f32_16x16x32_bf16(af, wf, acc[nt], 0, 0, 0);
      }
    }
  }
#pragma unroll
  for (int nt = 0; nt < 4; nt++){
    const int n  = n0 + nt * 16 + lb;
    const int wv = n >> (UB + 2);
    const int g  = (n >> UB) & 3;
    const int w  = n & ((1 << UB) - 1);
    const int q  = w >> 4;
    const int u  = w & 15;
    const int gq = g * NQ + q;
    const size_t nbase = (size_t)wv * VS + (size_t)(gq >> 1) * 256 + (size_t)(u >> 2) * 64
                       + (size_t)(gq & 1) * 4 + (size_t)(u & 3);
#pragma unroll
    for (int j = 0; j < 4; j += 2){
      const u32 pk = cvtpk(acc[nt][j], acc[nt][j + 1]);
#pragma unroll
      for (int s = 0; s < 2; ++s){
        const int m = m0 + v * 16 + lq * 4 + j + s;
        const int t = ENC_MAP ? (m & 255) : (m >> 8);
        const int b = ENC_MAP ? (m >> 8)  : (m & 255);
        outp[(size_t)t * TS + (size_t)(b >> 3) * WS + (size_t)(b & 7) * 8 + nbase]
            = (u16)(s ? (pk >> 16) : (pk & 0xffffu));
      }
    }
  }
}

// ---------- persistent recurrence ----------
// Grid 32 wgs; wg owns batch slice of 8 (MFMA N-cols 8..15 dead). Weights = A operand
// (M = gate rows, pre-permuted), h = B operand (N = batch). Wave v owns rows
// [v*NMT*16, (v+1)*NMT*16). Frag idx = kc*NMT+mt: [0,F_REG) in regs, rest in per-wave
// LDS. Full residency: F_REG+F_LDS == NMT*NKC (no L2 streaming).
// h double-buffered in LDS: read buf (t&1), write buf (t&1)^1, ONE barrier per step.
// xp: uint4 xq[NCH] holds the whole step (chunk i covers gq=2i,2i+1); chunk reloaded
// in place for t+1 after its last consumer -> global latency fully hidden.
template<int KDIM, int NWAVE, int NMT, int NKC, int NQ, int F_REG, int F_LDS, bool IS_DEC>
__global__ __launch_bounds__(NWAVE * 64, 1) void k_rec(const u16* __restrict__ Wp, const u16* __restrict__ xp,
                                                       u16* __restrict__ enc_out, float* __restrict__ out){
  constexpr int HP = KDIM + 8;              // padded h row (breaks 512B-stride bank aliasing)
  constexpr int NCH = 2 * NQ;
  constexpr size_t XSTR_T = (size_t)32 * NWAVE * NCH * 256;   // u16 per timestep
  static_assert(NMT == 4 * NQ, "tiles = 4 gates x NQ unit groups");
  static_assert(F_REG + F_LDS == NMT * NKC, "full on-chip residency");
  extern __shared__ u16 smem[];
  u16* hbuf = smem;                          // [2][8][HP]
  u16* al   = smem + 2 * 8 * HP;             // [NWAVE][F_LDS][512]
  const int tid = threadIdx.x, l = tid & 63, v = tid >> 6;
  const int lb = l & 15, lq = l >> 4;
  const int b0 = blockIdx.x * 8;
  const u16* wwave = Wp + (size_t)(v * (NMT * 16) + lb) * KDIM + lq * 8;
  u16* alw = al + (size_t)v * F_LDS * 512;

  // one-time weight load: frag layout A[m=lane&15][k=quad*8+j]
  bf16x8 Areg[(F_REG > 0) ? F_REG : 1];
#pragma unroll
  for (int kc = 0; kc < NKC; ++kc)
#pragma unroll
    for (int mt = 0; mt < NMT; ++mt){
      const int idx = kc * NMT + mt;
      const u16* src = wwave + (size_t)(mt * 16) * KDIM + kc * 32;
      if (idx < F_REG) Areg[idx] = *(const bf16x8*)src;
      else             *(bf16x8*)&alw[(idx - F_REG) * 512 + l * 8] = *(const bf16x8*)src;
    }

  // xp lane base for this (wg, wave): chunk i at +i*256 u16 (coalesced 512B per chunk)
  const u16* xpl = xp + ((size_t)blockIdx.x * NWAVE + v) * ((size_t)NCH * 256) + lq * 64 + lb * 8;
  uint4 xq[NCH] = {};
  if (lb < 8){
#pragma unroll
    for (int i = 0; i < NCH; ++i) xq[i] = *(const uint4*)(xpl + (size_t)i * 256);
  }

  for (int i = tid; i < 8 * HP; i += NWAVE * 64) hbuf[i] = 0;   // h(-1) = 0 (buf 0)
  float c[NQ][4];
#pragma unroll
  for (int q = 0; q < NQ; q++)
#pragma unroll
    for (int j = 0; j < 4; j++) c[q][j] = 0.f;
  __syncthreads();

  for (int t = 0; t < T_N; ++t){
    const u16* hrd = hbuf + (size_t)(t & 1) * (8 * HP);
    u16*       hwr = hbuf + (size_t)((t & 1) ^ 1) * (8 * HP);

    // h(t-1) B-frags: B[k=quad*8+j][n=lane&15] = h[b=n][k]; cols n>=8 garbage, never read
    bf16x8 Bh[NKC];
#pragma unroll
    for (int kc = 0; kc < NKC; ++kc)
      Bh[kc] = *(const bf16x8*)&hrd[lb * HP + kc * 32 + lq * 8];

    float4 osv[IS_DEC ? NQ : 1];   // fp32 out for post-barrier global store (dec only)
#pragma unroll
    for (int q = 0; q < NQ; ++q){
      f32x4 acc[4];
#pragma unroll
      for (int g = 0; g < 4; ++g){ f32x4 zz = {0.f, 0.f, 0.f, 0.f}; acc[g] = zz; }
#pragma unroll
      for (int kc = 0; kc < NKC; ++kc)
#pragma unroll
        for (int g = 0; g < 4; ++g){
          const int idx = kc * NMT + g * NQ + q;
          bf16x8 af;
          if (idx < F_REG) af = Areg[idx];
          else             af = *(const bf16x8*)&alw[(idx - F_REG) * 512 + l * 8];
          acc[g] = __builtin_amdgcn_mfma_f32_16x16x32_bf16(af, Bh[kc], acc[g], 0, 0, 0);
        }
      // xp extraction: compile-time chunk/half selects, zero VALU
      uint2 xr[4];
#pragma unroll
      for (int g = 0; g < 4; ++g){
        const int gq = g * NQ + q;
        const uint4 cx = xq[gq >> 1];
        if (gq & 1){ xr[g].x = cx.z; xr[g].y = cx.w; } else { xr[g].x = cx.x; xr[g].y = cx.y; }
      }
      // gates: acc[0..3] + xp = i,f,g,o pre-acts for same (b,u) per lane/reg
      float hv[4];
#pragma unroll
      for (int j = 0; j < 4; ++j){
        float iv = sigm(acc[0][j] + xpj(xr[0], j));
        float fv = sigm(acc[1][j] + xpj(xr[1], j));
        float gv = tanh_f(acc[2][j] + xpj(xr[2], j));
        float ov = sigm(acc[3][j] + xpj(xr[3], j));
        float cc = fv * c[q][j] + iv * gv;
        c[q][j] = cc;
        hv[j] = ov * tanh_f(cc);
      }
      // reload consumed chunks with t+1 data (even chunks after q1, odd after q3;
      // NQ==1: both after q0). ~1500+ cyc of MFMA/VALU/barrier before first use.
      if (t + 1 < T_N && lb < 8){
        if constexpr (NQ == 4){
          if ((q & 1) == 1){
            const int par = q >> 1;
#pragma unroll
            for (int i = 0; i < NCH; i += 2)
              xq[i + par] = *(const uint4*)(xpl + XSTR_T + (size_t)(i + par) * 256);
          }
        } else {
#pragma unroll
          for (int i = 0; i < NCH; ++i)
            xq[i] = *(const uint4*)(xpl + XSTR_T + (size_t)i * 256);
        }
      }
      if (lb < 8){
        const int u0 = v * (NQ * 16) + q * 16 + lq * 4;
        uint2 hp; hp.x = cvtpk(hv[0], hv[1]); hp.y = cvtpk(hv[2], hv[3]);
        *(uint2*)&hwr[lb * HP + u0] = hp;
        if (IS_DEC) osv[q] = make_float4(hv[0], hv[1], hv[2], hv[3]);
      }
    }
    __syncthreads();   // h(t) visible; global stores AFTER so vmcnt drain overlaps next step
    if (lb < 8){
#pragma unroll
      for (int q = 0; q < NQ; ++q){
        const int u0 = v * (NQ * 16) + q * 16 + lq * 4;
        if (!IS_DEC){
          const uint2 hp = *(const uint2*)&hwr[lb * HP + u0];   // re-read (saves hsv regs)
          *(uint2*)(enc_out + (size_t)(t * 256 + b0 + lb) * KDIM + u0) = hp;
        } else {
          *(float4*)(out + ((size_t)(b0 + lb) * T_N + t) * D_N + u0) = osv[q];
        }
      }
    }
    xpl += XSTR_T;
  }
}

extern "C" void kernel_launch(void* const* d_in, const int* in_sizes, int n_in,
                              void* d_out, int out_size, void* d_ws, size_t ws_size,
                              hipStream_t stream){
  const float* x    = (const float*)d_in[0];
  const float* eWih = (const float*)d_in[1];
  const float* eWhh = (const float*)d_in[2];
  const float* ebih = (const float*)d_in[3];
  const float* ebhh = (const float*)d_in[4];
  const float* dWih = (const float*)d_in[5];
  const float* dWhh = (const float*)d_in[6];
  const float* dbih = (const float*)d_in[7];
  const float* dbhh = (const float*)d_in[8];
  float* out = (float*)d_out;

  char* w = (char*)d_ws;
  size_t off = 0;
  auto carve = [&](size_t bytes) -> void* { void* p = w + off; off = (off + bytes + 255) & ~(size_t)255; return p; };
  u16*   xb    = (u16*)carve((size_t)B_N * T_N * D_N * 2);          // x in bf16
  u16*   WihEp = (u16*)carve((size_t)4 * H_N * D_N * 2);            // permuted enc Wih (UB=6,VB=2)
  u16*   WhhEp = (u16*)carve((size_t)4 * H_N * H_N * 2);            // permuted enc Whh (UB=6,VB=2)
  u16*   WihDp = (u16*)carve((size_t)4 * D_N * H_N * 2);            // permuted dec Wih (UB=4,VB=3)
  u16*   WhhDp = (u16*)carve((size_t)4 * D_N * D_N * 2);            // permuted dec Whh (UB=4,VB=3)
  float* bE    = (float*)carve((size_t)4 * H_N * 4);
  float* bD    = (float*)carve((size_t)4 * D_N * 4);
  u16*   xpE   = (u16*)carve((size_t)T_N * B_N * 4 * H_N * 2);      // swizzled [t][wg][v][ch][lq][bl][8]
  u16*   enc   = (u16*)carve((size_t)T_N * B_N * H_N * 2);          // encoded [T][B][H] bf16
  u16*   xpD   = (u16*)carve((size_t)T_N * B_N * 4 * D_N * 2);      // swizzled, dec
  (void)ws_size; (void)in_sizes; (void)n_in; (void)out_size;

  hipLaunchKernelGGL(k_cvt, dim3((B_N * T_N * D_N) / 1024), dim3(256), 0, stream, x, xb, B_N * T_N * D_N);
  hipLaunchKernelGGL(k_permW, dim3(1024), dim3(128), 0, stream, eWih, WihEp, 128, 6, 2);
  hipLaunchKernelGGL(k_permW, dim3(1024), dim3(128), 0, stream, eWhh, WhhEp, 256, 6, 2);
  hipLaunchKernelGGL(k_permW, dim3(512),  dim3(128), 0, stream, dWih, WihDp, 256, 4, 3);
  hipLaunchKernelGGL(k_permW, dim3(512),  dim3(128), 0, stream, dWhh, WhhDp, 128, 4, 3);
  hipLaunchKernelGGL(k_permB, dim3(1), dim3(256), 0, stream, ebih, ebhh, bE, 1024, 6, 2);
  hipLaunchKernelGGL(k_permB, dim3(1), dim3(256), 0, stream, dbih, dbhh, bD, 512, 4, 3);

  // enc x-proj: [65536,1024] = xb @ WihEp^T  (A rows m=b*T+t)
  hipLaunchKernelGGL((k_xproj<128, true, 6, 2>),  dim3(1024, 16), dim3(256), 0, stream, xb,  WihEp, bE, xpE);
  // enc recurrence: 4 waves, 16 Mtiles x 8 kc, 91 reg frags + 37 LDS frags (zero streaming)
  // LDS: 2*8*264*2 + 4*37*1024 = 160000 B
  hipLaunchKernelGGL((k_rec<256, 4, 16, 8, 4, 91, 37, false>), dim3(32), dim3(256),
                     2 * 8 * (H_N + 8) * 2 + 4 * 37 * 1024, stream, WhhEp, xpE, enc, (float*)nullptr);
  // dec x-proj: [65536,512] = enc @ WihDp^T (A rows m=t*B+b)
  hipLaunchKernelGGL((k_xproj<256, false, 4, 3>), dim3(1024, 8),  dim3(256), 0, stream, enc, WihDp, bD, xpD);
  // dec recurrence: 8 waves (2/SIMD), 4 Mtiles x 4 kc, all 16 frags in regs; fp32 out
  hipLaunchKernelGGL((k_rec<128, 8, 4, 4, 1, 16, 0, true>),  dim3(32), dim3(512),
                     2 * 8 * (D_N + 8) * 2, stream, WhhDp, xpD, (u16*)nullptr, out);
}

// Round 3
// 1309.096 us; speedup vs baseline: 1.3243x; 1.1457x over previous
//
#include <hip/hip_runtime.h>
#include <stdint.h>

// LSTM autoencoder: B=256,T=256,D=128,H=256, gate order i,f,g,o.
// R1: persistent recurrence, full on-chip weight residency, double-buffered h.
// R2: perm fix for 8-wave dec.
// R3: pre-swizzled xp (coalesced dwordx4 reload in place), cvt_pk, unconditional Bh.
// R4: enc recurrence -> 2 waves/SIMD (8 waves/wg, NMT=8, NQ=2). Residency: 44 frags
//     in regs + 18 in LDS per wave + 2 streamed from L1/L2 via volatile loads (fixed
//     addr every step -> L1-hit; volatile blocks LICM reg-inflation). Bh streamed
//     per-(q,kc). xp chunk order qg=q*4+g: phase q consumes chunks {2q,2q+1}, reloads
//     right after extraction. launch_bounds(waves*64, waves/4) caps VGPR at 256.
// R5: fix compile error — volatile load via ext_vector u32 (HIP uint4 is a class type,
//     volatile-copy is ill-formed; builtin vectors load fine and keep dwordx4).

#define B_N 256
#define T_N 256
#define D_N 128
#define H_N 256

typedef __attribute__((ext_vector_type(8))) short bf16x8;  // MFMA A/B frag (4 VGPRs)
typedef __attribute__((ext_vector_type(4))) float f32x4;   // MFMA C/D frag
typedef unsigned short u16;
typedef unsigned int u32;
typedef __attribute__((ext_vector_type(4))) u32 u32v4;     // builtin vec: volatile-loadable

__device__ __forceinline__ float bflo(u32 u){ return __uint_as_float(u << 16); }
__device__ __forceinline__ float bfhi(u32 u){ return __uint_as_float(u & 0xffff0000u); }
__device__ __forceinline__ u32 f2bf_bits(float f){ u32 u = __float_as_uint(f); return (u + 0x7fffu + ((u >> 16) & 1u)) >> 16; }
__device__ __forceinline__ u32 pack2(float lo, float hi){ return f2bf_bits(lo) | (f2bf_bits(hi) << 16); }
__device__ __forceinline__ u32 cvtpk(float lo, float hi){ u32 r; asm("v_cvt_pk_bf16_f32 %0, %1, %2" : "=v"(r) : "v"(lo), "v"(hi)); return r; }
__device__ __forceinline__ float sigm(float x){ return __builtin_amdgcn_rcpf(1.f + __expf(-x)); }
__device__ __forceinline__ float tanh_f(float x){ return 1.f - 2.f * __builtin_amdgcn_rcpf(1.f + __expf(2.f * x)); }
__device__ __forceinline__ float xpj(uint2 r, int j){
  return j == 0 ? bflo(r.x) : j == 1 ? bfhi(r.x) : j == 2 ? bflo(r.y) : bfhi(r.y);
}

// ---------- prep kernels ----------
__global__ void k_cvt(const float* __restrict__ src, u16* __restrict__ dst, int n){
  int i = (blockIdx.x * blockDim.x + threadIdx.x) * 4;
  if (i >= n) return;
  float4 v = *(const float4*)(src + i);
  uint2 o; o.x = pack2(v.x, v.y); o.y = pack2(v.z, v.w);
  *(uint2*)(dst + i) = o;
}

// Row permutation p -> orig so that wave v (of 1<<VB waves) owns rows
// [v*4U,(v+1)*4U) = {i,f,g,o} x units[v*U,(v+1)*U), U = 1<<UB units/wave.
// p = (v << (UB+2)) | (g << UB) | uo  ;  orig = (g << (UB+VB)) | (v << UB) | uo
__global__ void k_permW(const float* __restrict__ W, u16* __restrict__ Wp, int K, int UB, int VB){
  int p = blockIdx.x;
  int uo = p & ((1 << UB) - 1), g = (p >> UB) & 3, v = p >> (UB + 2);
  int orig = (g << (UB + VB)) | (v << UB) | uo;
  for (int k = threadIdx.x; k < K; k += blockDim.x)
    Wp[(size_t)p * K + k] = (u16)f2bf_bits(W[(size_t)orig * K + k]);
}

__global__ void k_permB(const float* __restrict__ b1, const float* __restrict__ b2,
                        float* __restrict__ bp, int P, int UB, int VB){
  for (int p = threadIdx.x; p < P; p += blockDim.x){
    int uo = p & ((1 << UB) - 1), g = (p >> UB) & 3, v = p >> (UB + 2);
    int orig = (g << (UB + VB)) | (v << UB) | uo;
    bp[p] = b1[orig] + b2[orig];
  }
}

// ---------- input-projection GEMM: out[m,n] = sum_k A[m,k]*W[n,k] + bias[n] ----------
// Output layout (consumed by k_rec): with n=p -> wv=p>>(UB+2), g=(p>>UB)&3,
// q=(p&mask)>>4, u=p&15, qg=q*4+g, ch=qg>>1, half=qg&1:
// u16 idx = t*TS + (b>>3)*WS + wv*VS + ch*256 + (u>>2)*64 + (b&7)*8 + half*4 + (u&3).
// Phase q of k_rec consumes exactly chunks {2q, 2q+1}.
template<int KTOT, bool ENC_MAP, int UB, int VB>
__global__ __launch_bounds__(256, 1) void k_xproj(const u16* __restrict__ A, const u16* __restrict__ W,
                                                  const float* __restrict__ bias, u16* __restrict__ outp){
  constexpr int NQ  = 1 << (UB - 4);
  constexpr int NCH = 2 * NQ;
  constexpr size_t VS = (size_t)NCH * 256;
  constexpr size_t WS = (size_t)(1 << VB) * VS;
  constexpr size_t TS = 32 * WS;
  __shared__ u16 As[64][72];
  __shared__ u16 Ws[64][72];
  const int tid = threadIdx.x, l = tid & 63, v = tid >> 6;
  const int lb = l & 15, lq = l >> 4;
  const int m0 = blockIdx.x * 64, n0 = blockIdx.y * 64;
  f32x4 acc[4];
#pragma unroll
  for (int nt = 0; nt < 4; nt++){ float bv = bias[n0 + nt * 16 + lb]; f32x4 t = {bv, bv, bv, bv}; acc[nt] = t; }
  const int r = tid >> 3, c8 = (tid & 7) * 8;
  for (int kb = 0; kb < KTOT / 64; ++kb){
    __syncthreads();
    *(bf16x8*)&As[r][c8]      = *(const bf16x8*)&A[(size_t)(m0 + r) * KTOT + kb * 64 + c8];
    *(bf16x8*)&As[r + 32][c8] = *(const bf16x8*)&A[(size_t)(m0 + r + 32) * KTOT + kb * 64 + c8];
    *(bf16x8*)&Ws[r][c8]      = *(const bf16x8*)&W[(size_t)(n0 + r) * KTOT + kb * 64 + c8];
    *(bf16x8*)&Ws[r + 32][c8] = *(const bf16x8*)&W[(size_t)(n0 + r + 32) * KTOT + kb * 64 + c8];
    __syncthreads();
#pragma unroll
    for (int kc = 0; kc < 2; kc++){
      bf16x8 af = *(const bf16x8*)&As[v * 16 + lb][kc * 32 + lq * 8];
#pragma unroll
      for (int nt = 0; nt < 4; nt++){
        bf16x8 wf = *(const bf16x8*)&Ws[nt * 16 + lb][kc * 32 + lq * 8];
        acc[nt] = __builtin_amdgcn_mfma_f32_16x16x32_bf16(af, wf, acc[nt], 0, 0, 0);
      }
    }
  }
#pragma unroll
  for (int nt = 0; nt < 4; nt++){
    const int n  = n0 + nt * 16 + lb;
    const int wv = n >> (UB + 2);
    const int g  = (n >> UB) & 3;
    const int w  = n & ((1 << UB) - 1);
    const int q  = w >> 4;
    const int u  = w & 15;
    const int qg = q * 4 + g;
    const size_t nbase = (size_t)wv * VS + (size_t)(qg >> 1) * 256 + (size_t)(u >> 2) * 64
                       + (size_t)(qg & 1) * 4 + (size_t)(u & 3);
#pragma unroll
    for (int j = 0; j < 4; j += 2){
      const u32 pk = cvtpk(acc[nt][j], acc[nt][j + 1]);
#pragma unroll
      for (int s = 0; s < 2; ++s){
        const int m = m0 + v * 16 + lq * 4 + j + s;
        const int t = ENC_MAP ? (m & 255) : (m >> 8);
        const int b = ENC_MAP ? (m >> 8)  : (m & 255);
        outp[(size_t)t * TS + (size_t)(b >> 3) * WS + (size_t)(b & 7) * 8 + nbase]
            = (u16)(s ? (pk >> 16) : (pk & 0xffffu));
      }
    }
  }
}

// ---------- persistent recurrence ----------
// Grid 32 wgs; wg owns batch slice of 8 (MFMA N-cols 8..15 dead). Weights = A operand
// (M = gate rows, pre-permuted), h = B operand (N = batch). Wave v owns rows
// [v*NMT*16, (v+1)*NMT*16). Frag idx = kc*NMT+mt: [0,F_REG) in regs, [F_REG,F_REG+F_LDS)
// in per-wave LDS, rest read from global each step (fixed addr -> L1-resident; volatile
// so LICM can't hoist them back into registers).
// h double-buffered in LDS: read buf (t&1), write buf (t&1)^1, ONE barrier per step.
// Bh streamed per-(q,kc) from LDS (no preload; co-resident wave hides latency).
// xp: uint4 xq[NCH]; phase q extracts chunks {2q,2q+1}, then immediately reloads them
// with t+1 data (before the gate VALU) -> >=1 phase + barrier of lead.
template<int KDIM, int NWAVE, int NMT, int NKC, int NQ, int F_REG, int F_LDS, bool IS_DEC>
__global__ __launch_bounds__(NWAVE * 64, NWAVE / 4) void k_rec(const u16* __restrict__ Wp, const u16* __restrict__ xp,
                                                               u16* __restrict__ enc_out, float* __restrict__ out){
  constexpr int HP = KDIM + 8;              // padded h row (breaks 512B-stride bank aliasing)
  constexpr int NCH = 2 * NQ;
  constexpr size_t XSTR_T = (size_t)32 * NWAVE * NCH * 256;   // u16 per timestep
  static_assert(NMT == 4 * NQ, "tiles = 4 gates x NQ unit groups");
  static_assert(F_REG + F_LDS <= NMT * NKC, "reg+LDS tiers within total frags");
  extern __shared__ u16 smem[];
  u16* hbuf = smem;                          // [2][8][HP]
  u16* al   = smem + 2 * 8 * HP;             // [NWAVE][F_LDS][512]
  const int tid = threadIdx.x, l = tid & 63, v = tid >> 6;
  const int lb = l & 15, lq = l >> 4;
  const int b0 = blockIdx.x * 8;
  const u16* wwave = Wp + (size_t)(v * (NMT * 16) + lb) * KDIM + lq * 8;
  u16* alw = al + (size_t)v * F_LDS * 512;

  // one-time weight load: frag layout A[m=lane&15][k=quad*8+j]
  bf16x8 Areg[(F_REG > 0) ? F_REG : 1];
#pragma unroll
  for (int kc = 0; kc < NKC; ++kc)
#pragma unroll
    for (int mt = 0; mt < NMT; ++mt){
      const int idx = kc * NMT + mt;
      const u16* src = wwave + (size_t)(mt * 16) * KDIM + kc * 32;
      if (idx < F_REG)              Areg[idx] = *(const bf16x8*)src;
      else if (idx < F_REG + F_LDS) *(bf16x8*)&alw[(idx - F_REG) * 512 + l * 8] = *(const bf16x8*)src;
      // idx >= F_REG+F_LDS: stays in global (L1-resident; read per step)
    }

  // xp lane base for this (wg, wave): chunk i at +i*256 u16 (coalesced 512B per chunk)
  const u16* xpl = xp + ((size_t)blockIdx.x * NWAVE + v) * ((size_t)NCH * 256) + lq * 64 + lb * 8;
  uint4 xq[NCH] = {};
  if (lb < 8){
#pragma unroll
    for (int i = 0; i < NCH; ++i) xq[i] = *(const uint4*)(xpl + (size_t)i * 256);
  }

  for (int i = tid; i < 8 * HP; i += NWAVE * 64) hbuf[i] = 0;   // h(-1) = 0 (buf 0)
  float c[NQ][4];
#pragma unroll
  for (int q = 0; q < NQ; q++)
#pragma unroll
    for (int j = 0; j < 4; j++) c[q][j] = 0.f;
  __syncthreads();

  for (int t = 0; t < T_N; ++t){
    const u16* hrd = hbuf + (size_t)(t & 1) * (8 * HP);
    u16*       hwr = hbuf + (size_t)((t & 1) ^ 1) * (8 * HP);

    float4 osv[IS_DEC ? NQ : 1];   // fp32 out for post-barrier global store (dec only)
#pragma unroll
    for (int q = 0; q < NQ; ++q){
      f32x4 acc[4];
#pragma unroll
      for (int g = 0; g < 4; ++g){ f32x4 zz = {0.f, 0.f, 0.f, 0.f}; acc[g] = zz; }
#pragma unroll
      for (int kc = 0; kc < NKC; ++kc){
        // h(t-1) B-frag: B[k=quad*8+j][n=lane&15] = h[b=n][k]; cols n>=8 garbage, never read
        const bf16x8 bh = *(const bf16x8*)&hrd[lb * HP + kc * 32 + lq * 8];
#pragma unroll
        for (int g = 0; g < 4; ++g){
          const int idx = kc * NMT + g * NQ + q;
          bf16x8 af;
          if (idx < F_REG)              af = Areg[idx];
          else if (idx < F_REG + F_LDS) af = *(const bf16x8*)&alw[(idx - F_REG) * 512 + l * 8];
          else {                         // L1-resident global tier; volatile defeats LICM
            const int mt = g * NQ + q;
            u32v4 gw = *(const volatile u32v4*)(wwave + (size_t)(mt * 16) * KDIM + kc * 32);
            af = __builtin_bit_cast(bf16x8, gw);
          }
          acc[g] = __builtin_amdgcn_mfma_f32_16x16x32_bf16(af, bh, acc[g], 0, 0, 0);
        }
      }
      // xp extraction: compile-time chunk/half selects, zero VALU
      uint2 xr[4];
#pragma unroll
      for (int g = 0; g < 4; ++g){
        const uint4 cx = xq[(q * 4 + g) >> 1];
        if (g & 1){ xr[g].x = cx.z; xr[g].y = cx.w; } else { xr[g].x = cx.x; xr[g].y = cx.y; }
      }
      // reload the two chunks this phase consumed with t+1 data (issued before the gate
      // VALU -> extra ~400cyc lead; consumed next step same phase).
      if (t + 1 < T_N && lb < 8){
#pragma unroll
        for (int i = 0; i < 2; ++i){
          const int ch = q * 2 + i;
          if (ch < NCH) xq[ch] = *(const uint4*)(xpl + XSTR_T + (size_t)ch * 256);
        }
      }
      // gates: acc[0..3] + xp = i,f,g,o pre-acts for same (b,u) per lane/reg
      float hv[4];
#pragma unroll
      for (int j = 0; j < 4; ++j){
        float iv = sigm(acc[0][j] + xpj(xr[0], j));
        float fv = sigm(acc[1][j] + xpj(xr[1], j));
        float gv = tanh_f(acc[2][j] + xpj(xr[2], j));
        float ov = sigm(acc[3][j] + xpj(xr[3], j));
        float cc = fv * c[q][j] + iv * gv;
        c[q][j] = cc;
        hv[j] = ov * tanh_f(cc);
      }
      if (lb < 8){
        const int u0 = v * (NQ * 16) + q * 16 + lq * 4;
        uint2 hp; hp.x = cvtpk(hv[0], hv[1]); hp.y = cvtpk(hv[2], hv[3]);
        *(uint2*)&hwr[lb * HP + u0] = hp;
        if (IS_DEC) osv[q] = make_float4(hv[0], hv[1], hv[2], hv[3]);
      }
    }
    __syncthreads();   // h(t) visible; global stores AFTER so vmcnt drain overlaps next step
    if (lb < 8){
#pragma unroll
      for (int q = 0; q < NQ; ++q){
        const int u0 = v * (NQ * 16) + q * 16 + lq * 4;
        if (!IS_DEC){
          const uint2 hp = *(const uint2*)&hwr[lb * HP + u0];   // re-read (saves hsv regs)
          *(uint2*)(enc_out + (size_t)(t * 256 + b0 + lb) * KDIM + u0) = hp;
        } else {
          *(float4*)(out + ((size_t)(b0 + lb) * T_N + t) * D_N + u0) = osv[q];
        }
      }
    }
    xpl += XSTR_T;
  }
}

extern "C" void kernel_launch(void* const* d_in, const int* in_sizes, int n_in,
                              void* d_out, int out_size, void* d_ws, size_t ws_size,
                              hipStream_t stream){
  const float* x    = (const float*)d_in[0];
  const float* eWih = (const float*)d_in[1];
  const float* eWhh = (const float*)d_in[2];
  const float* ebih = (const float*)d_in[3];
  const float* ebhh = (const float*)d_in[4];
  const float* dWih = (const float*)d_in[5];
  const float* dWhh = (const float*)d_in[6];
  const float* dbih = (const float*)d_in[7];
  const float* dbhh = (const float*)d_in[8];
  float* out = (float*)d_out;

  char* w = (char*)d_ws;
  size_t off = 0;
  auto carve = [&](size_t bytes) -> void* { void* p = w + off; off = (off + bytes + 255) & ~(size_t)255; return p; };
  u16*   xb    = (u16*)carve((size_t)B_N * T_N * D_N * 2);          // x in bf16
  u16*   WihEp = (u16*)carve((size_t)4 * H_N * D_N * 2);            // permuted enc Wih (UB=5,VB=3)
  u16*   WhhEp = (u16*)carve((size_t)4 * H_N * H_N * 2);            // permuted enc Whh (UB=5,VB=3)
  u16*   WihDp = (u16*)carve((size_t)4 * D_N * H_N * 2);            // permuted dec Wih (UB=4,VB=3)
  u16*   WhhDp = (u16*)carve((size_t)4 * D_N * D_N * 2);            // permuted dec Whh (UB=4,VB=3)
  float* bE    = (float*)carve((size_t)4 * H_N * 4);
  float* bD    = (float*)carve((size_t)4 * D_N * 4);
  u16*   xpE   = (u16*)carve((size_t)T_N * B_N * 4 * H_N * 2);      // swizzled [t][wg][v][ch][lq][bl][8]
  u16*   enc   = (u16*)carve((size_t)T_N * B_N * H_N * 2);          // encoded [T][B][H] bf16
  u16*   xpD   = (u16*)carve((size_t)T_N * B_N * 4 * D_N * 2);      // swizzled, dec
  (void)ws_size; (void)in_sizes; (void)n_in; (void)out_size;

  hipLaunchKernelGGL(k_cvt, dim3((B_N * T_N * D_N) / 1024), dim3(256), 0, stream, x, xb, B_N * T_N * D_N);
  hipLaunchKernelGGL(k_permW, dim3(1024), dim3(128), 0, stream, eWih, WihEp, 128, 5, 3);
  hipLaunchKernelGGL(k_permW, dim3(1024), dim3(128), 0, stream, eWhh, WhhEp, 256, 5, 3);
  hipLaunchKernelGGL(k_permW, dim3(512),  dim3(128), 0, stream, dWih, WihDp, 256, 4, 3);
  hipLaunchKernelGGL(k_permW, dim3(512),  dim3(128), 0, stream, dWhh, WhhDp, 128, 4, 3);
  hipLaunchKernelGGL(k_permB, dim3(1), dim3(256), 0, stream, ebih, ebhh, bE, 1024, 5, 3);
  hipLaunchKernelGGL(k_permB, dim3(1), dim3(256), 0, stream, dbih, dbhh, bD, 512, 4, 3);

  // enc x-proj: [65536,1024] = xb @ WihEp^T  (A rows m=b*T+t)
  hipLaunchKernelGGL((k_xproj<128, true, 5, 3>),  dim3(1024, 16), dim3(256), 0, stream, xb,  WihEp, bE, xpE);
  // enc recurrence: 8 waves (2/SIMD), 8 Mtiles x 8 kc, 44 reg + 18 LDS + 2 global frags
  // LDS: 2*8*264*2 + 8*18*1024 = 155904 B
  hipLaunchKernelGGL((k_rec<256, 8, 8, 8, 2, 44, 18, false>), dim3(32), dim3(512),
                     2 * 8 * (H_N + 8) * 2 + 8 * 18 * 1024, stream, WhhEp, xpE, enc, (float*)nullptr);
  // dec x-proj: [65536,512] = enc @ WihDp^T (A rows m=t*B+b)
  hipLaunchKernelGGL((k_xproj<256, false, 4, 3>), dim3(1024, 8),  dim3(256), 0, stream, enc, WihDp, bD, xpD);
  // dec recurrence: 8 waves (2/SIMD), 4 Mtiles x 4 kc, all 16 frags in regs; fp32 out
  // (+4KB LDS slack so lb>=8 garbage Bh reads stay inside the allocation)
  hipLaunchKernelGGL((k_rec<128, 8, 4, 4, 1, 16, 0, true>),  dim3(32), dim3(512),
                     2 * 8 * (D_N + 8) * 2 + 4096, stream, WhhDp, xpD, (u16*)nullptr, out);
}

// Round 4
// 1241.995 us; speedup vs baseline: 1.3959x; 1.0540x over previous
//
#include <hip/hip_runtime.h>
#include <stdint.h>

// LSTM autoencoder: B=256,T=256,D=128,H=256, gate order i,f,g,o.
// R1: persistent recurrence, full on-chip weight residency, double-buffered h.
// R2: perm fix for 8-wave dec.
// R3: pre-swizzled xp (coalesced dwordx4 reload in place), cvt_pk, unconditional Bh.
// R4/R5: enc recurrence 2 waves/SIMD (8 waves, NMT=8, NQ=2); 44 reg + 18 LDS + 2
//     L1-resident global frags; streamed Bh; per-phase xp chunk reload.
// R6: (a) conflict-free h layout: hbuf stored in B-frag order, u16
//     idx(b,k) = (k>>5)*512 + ((k>>3)&3)*128 + b*8 + (k&7); Bh read becomes
//     hrd[kc*512 + l*8] = contiguous 1KB per wave (zero bank conflict; write is
//     2-way = free). R5 had 4.19M conflict cycles (~7%/step) on the padded layout.
//     (b) acc initialized from xp (kills zero-init + post-MFMA adds, shorter chain).
//     (c) xp reload issued BEFORE the MFMA block; s_setprio(1) around MFMAs (T5).
//     enc LDS = 16384 + 8*18*1024 = 163840 B exactly.

#define B_N 256
#define T_N 256
#define D_N 128
#define H_N 256

typedef __attribute__((ext_vector_type(8))) short bf16x8;  // MFMA A/B frag (4 VGPRs)
typedef __attribute__((ext_vector_type(4))) float f32x4;   // MFMA C/D frag
typedef unsigned short u16;
typedef unsigned int u32;
typedef __attribute__((ext_vector_type(4))) u32 u32v4;     // builtin vec: volatile-loadable

__device__ __forceinline__ float bflo(u32 u){ return __uint_as_float(u << 16); }
__device__ __forceinline__ float bfhi(u32 u){ return __uint_as_float(u & 0xffff0000u); }
__device__ __forceinline__ u32 f2bf_bits(float f){ u32 u = __float_as_uint(f); return (u + 0x7fffu + ((u >> 16) & 1u)) >> 16; }
__device__ __forceinline__ u32 pack2(float lo, float hi){ return f2bf_bits(lo) | (f2bf_bits(hi) << 16); }
__device__ __forceinline__ u32 cvtpk(float lo, float hi){ u32 r; asm("v_cvt_pk_bf16_f32 %0, %1, %2" : "=v"(r) : "v"(lo), "v"(hi)); return r; }
__device__ __forceinline__ float sigm(float x){ return __builtin_amdgcn_rcpf(1.f + __expf(-x)); }
__device__ __forceinline__ float tanh_f(float x){ return 1.f - 2.f * __builtin_amdgcn_rcpf(1.f + __expf(2.f * x)); }

// ---------- prep kernels ----------
__global__ void k_cvt(const float* __restrict__ src, u16* __restrict__ dst, int n){
  int i = (blockIdx.x * blockDim.x + threadIdx.x) * 4;
  if (i >= n) return;
  float4 v = *(const float4*)(src + i);
  uint2 o; o.x = pack2(v.x, v.y); o.y = pack2(v.z, v.w);
  *(uint2*)(dst + i) = o;
}

// Row permutation p -> orig so that wave v (of 1<<VB waves) owns rows
// [v*4U,(v+1)*4U) = {i,f,g,o} x units[v*U,(v+1)*U), U = 1<<UB units/wave.
// p = (v << (UB+2)) | (g << UB) | uo  ;  orig = (g << (UB+VB)) | (v << UB) | uo
__global__ void k_permW(const float* __restrict__ W, u16* __restrict__ Wp, int K, int UB, int VB){
  int p = blockIdx.x;
  int uo = p & ((1 << UB) - 1), g = (p >> UB) & 3, v = p >> (UB + 2);
  int orig = (g << (UB + VB)) | (v << UB) | uo;
  for (int k = threadIdx.x; k < K; k += blockDim.x)
    Wp[(size_t)p * K + k] = (u16)f2bf_bits(W[(size_t)orig * K + k]);
}

__global__ void k_permB(const float* __restrict__ b1, const float* __restrict__ b2,
                        float* __restrict__ bp, int P, int UB, int VB){
  for (int p = threadIdx.x; p < P; p += blockDim.x){
    int uo = p & ((1 << UB) - 1), g = (p >> UB) & 3, v = p >> (UB + 2);
    int orig = (g << (UB + VB)) | (v << UB) | uo;
    bp[p] = b1[orig] + b2[orig];
  }
}

// ---------- input-projection GEMM: out[m,n] = sum_k A[m,k]*W[n,k] + bias[n] ----------
// Output layout (consumed by k_rec): with n=p -> wv=p>>(UB+2), g=(p>>UB)&3,
// q=(p&mask)>>4, u=p&15, qg=q*4+g, ch=qg>>1, half=qg&1:
// u16 idx = t*TS + (b>>3)*WS + wv*VS + ch*256 + (u>>2)*64 + (b&7)*8 + half*4 + (u&3).
// Phase q of k_rec consumes exactly chunks {2q, 2q+1}.
template<int KTOT, bool ENC_MAP, int UB, int VB>
__global__ __launch_bounds__(256, 1) void k_xproj(const u16* __restrict__ A, const u16* __restrict__ W,
                                                  const float* __restrict__ bias, u16* __restrict__ outp){
  constexpr int NQ  = 1 << (UB - 4);
  constexpr int NCH = 2 * NQ;
  constexpr size_t VS = (size_t)NCH * 256;
  constexpr size_t WS = (size_t)(1 << VB) * VS;
  constexpr size_t TS = 32 * WS;
  __shared__ u16 As[64][72];
  __shared__ u16 Ws[64][72];
  const int tid = threadIdx.x, l = tid & 63, v = tid >> 6;
  const int lb = l & 15, lq = l >> 4;
  const int m0 = blockIdx.x * 64, n0 = blockIdx.y * 64;
  f32x4 acc[4];
#pragma unroll
  for (int nt = 0; nt < 4; nt++){ float bv = bias[n0 + nt * 16 + lb]; f32x4 t = {bv, bv, bv, bv}; acc[nt] = t; }
  const int r = tid >> 3, c8 = (tid & 7) * 8;
  for (int kb = 0; kb < KTOT / 64; ++kb){
    __syncthreads();
    *(bf16x8*)&As[r][c8]      = *(const bf16x8*)&A[(size_t)(m0 + r) * KTOT + kb * 64 + c8];
    *(bf16x8*)&As[r + 32][c8] = *(const bf16x8*)&A[(size_t)(m0 + r + 32) * KTOT + kb * 64 + c8];
    *(bf16x8*)&Ws[r][c8]      = *(const bf16x8*)&W[(size_t)(n0 + r) * KTOT + kb * 64 + c8];
    *(bf16x8*)&Ws[r + 32][c8] = *(const bf16x8*)&W[(size_t)(n0 + r + 32) * KTOT + kb * 64 + c8];
    __syncthreads();
#pragma unroll
    for (int kc = 0; kc < 2; kc++){
      bf16x8 af = *(const bf16x8*)&As[v * 16 + lb][kc * 32 + lq * 8];
#pragma unroll
      for (int nt = 0; nt < 4; nt++){
        bf16x8 wf = *(const bf16x8*)&Ws[nt * 16 + lb][kc * 32 + lq * 8];
        acc[nt] = __builtin_amdgcn_mfma_f32_16x16x32_bf16(af, wf, acc[nt], 0, 0, 0);
      }
    }
  }
#pragma unroll
  for (int nt = 0; nt < 4; nt++){
    const int n  = n0 + nt * 16 + lb;
    const int wv = n >> (UB + 2);
    const int g  = (n >> UB) & 3;
    const int w  = n & ((1 << UB) - 1);
    const int q  = w >> 4;
    const int u  = w & 15;
    const int qg = q * 4 + g;
    const size_t nbase = (size_t)wv * VS + (size_t)(qg >> 1) * 256 + (size_t)(u >> 2) * 64
                       + (size_t)(qg & 1) * 4 + (size_t)(u & 3);
#pragma unroll
    for (int j = 0; j < 4; j += 2){
      const u32 pk = cvtpk(acc[nt][j], acc[nt][j + 1]);
#pragma unroll
      for (int s = 0; s < 2; ++s){
        const int m = m0 + v * 16 + lq * 4 + j + s;
        const int t = ENC_MAP ? (m & 255) : (m >> 8);
        const int b = ENC_MAP ? (m >> 8)  : (m & 255);
        outp[(size_t)t * TS + (size_t)(b >> 3) * WS + (size_t)(b & 7) * 8 + nbase]
            = (u16)(s ? (pk >> 16) : (pk & 0xffffu));
      }
    }
  }
}

// ---------- persistent recurrence ----------
// Grid 32 wgs; wg owns batch slice of 8 (MFMA N-cols 8..15 dead). Weights = A operand
// (M = gate rows, pre-permuted), h = B operand (N = batch). Wave v owns rows
// [v*NMT*16, (v+1)*NMT*16). Frag idx = kc*NMT+mt: [0,F_REG) in regs, [F_REG,F_REG+F_LDS)
// in per-wave LDS, rest volatile-read from global each step (fixed addr -> L1-hit).
// h double-buffered in LDS in B-FRAGMENT ORDER:
//   u16 idx(b,k) = (k>>5)*512 + ((k>>3)&3)*128 + b*8 + (k&7)
// so Bh read per (kc) = hrd[kc*512 + l*8]: contiguous 1KB, conflict-free; the h-write
// is a 2-way bank alias (free). b slots 8..15 are never written (stale zeros, only
// feed dead MFMA cols). ONE barrier per step.
// xp: uint4 xq[NCH]; phase q extracts chunks {2q,2q+1} into acc (C-operand init),
// then reloads them with t+1 data BEFORE the MFMA block -> max lead.
template<int KDIM, int NWAVE, int NMT, int NKC, int NQ, int F_REG, int F_LDS, bool IS_DEC>
__global__ __launch_bounds__(NWAVE * 64, NWAVE / 4) void k_rec(const u16* __restrict__ Wp, const u16* __restrict__ xp,
                                                               u16* __restrict__ enc_out, float* __restrict__ out){
  constexpr int BUFS = NKC * 512;           // u16 per h buffer (frag-order layout)
  constexpr int NCH = 2 * NQ;
  constexpr size_t XSTR_T = (size_t)32 * NWAVE * NCH * 256;   // u16 per timestep
  static_assert(NMT == 4 * NQ, "tiles = 4 gates x NQ unit groups");
  static_assert(F_REG + F_LDS <= NMT * NKC, "reg+LDS tiers within total frags");
  extern __shared__ u16 smem[];
  u16* hbuf = smem;                          // [2][BUFS]
  u16* al   = smem + 2 * BUFS;               // [NWAVE][F_LDS][512]
  const int tid = threadIdx.x, l = tid & 63, v = tid >> 6;
  const int lb = l & 15, lq = l >> 4;
  const int b0 = blockIdx.x * 8;
  const u16* wwave = Wp + (size_t)(v * (NMT * 16) + lb) * KDIM + lq * 8;
  u16* alw = al + (size_t)v * F_LDS * 512;

  // one-time weight load: frag layout A[m=lane&15][k=quad*8+j]
  bf16x8 Areg[(F_REG > 0) ? F_REG : 1];
#pragma unroll
  for (int kc = 0; kc < NKC; ++kc)
#pragma unroll
    for (int mt = 0; mt < NMT; ++mt){
      const int idx = kc * NMT + mt;
      const u16* src = wwave + (size_t)(mt * 16) * KDIM + kc * 32;
      if (idx < F_REG)              Areg[idx] = *(const bf16x8*)src;
      else if (idx < F_REG + F_LDS) *(bf16x8*)&alw[(idx - F_REG) * 512 + l * 8] = *(const bf16x8*)src;
      // idx >= F_REG+F_LDS: stays in global (L1-resident; read per step)
    }

  // xp lane base for this (wg, wave): chunk i at +i*256 u16 (coalesced 512B per chunk)
  const u16* xpl = xp + ((size_t)blockIdx.x * NWAVE + v) * ((size_t)NCH * 256) + lq * 64 + lb * 8;
  uint4 xq[NCH] = {};
  if (lb < 8){
#pragma unroll
    for (int i = 0; i < NCH; ++i) xq[i] = *(const uint4*)(xpl + (size_t)i * 256);
  }

  for (int i = tid; i < 2 * BUFS; i += NWAVE * 64) hbuf[i] = 0;   // h(-1)=0 + dead b-slots
  float c[NQ][4];
#pragma unroll
  for (int q = 0; q < NQ; q++)
#pragma unroll
    for (int j = 0; j < 4; j++) c[q][j] = 0.f;
  __syncthreads();

  for (int t = 0; t < T_N; ++t){
    const u16* hrd = hbuf + (size_t)(t & 1) * BUFS;
    u16*       hwr = hbuf + (size_t)((t & 1) ^ 1) * BUFS;

    float4 osv[IS_DEC ? NQ : 1];   // fp32 out for post-barrier global store (dec only)
#pragma unroll
    for (int q = 0; q < NQ; ++q){
      // xp extraction -> MFMA C-operand init (chunks loaded >=1 step ago)
      f32x4 acc[4];
#pragma unroll
      for (int g = 0; g < 4; ++g){
        const uint4 cx = xq[(q * 4 + g) >> 1];
        const u32 w0 = (g & 1) ? cx.z : cx.x;
        const u32 w1 = (g & 1) ? cx.w : cx.y;
        acc[g][0] = bflo(w0); acc[g][1] = bfhi(w0);
        acc[g][2] = bflo(w1); acc[g][3] = bfhi(w1);
      }
      // reload the two consumed chunks with t+1 data BEFORE the MFMA block
      if (t + 1 < T_N && lb < 8){
#pragma unroll
        for (int i = 0; i < 2; ++i){
          const int ch = q * 2 + i;
          if (ch < NCH) xq[ch] = *(const uint4*)(xpl + XSTR_T + (size_t)ch * 256);
        }
      }
      __builtin_amdgcn_s_setprio(1);
#pragma unroll
      for (int kc = 0; kc < NKC; ++kc){
        // h(t-1) B-frag: contiguous 1KB wave read, conflict-free
        const bf16x8 bh = *(const bf16x8*)&hrd[kc * 512 + l * 8];
#pragma unroll
        for (int g = 0; g < 4; ++g){
          const int idx = kc * NMT + g * NQ + q;
          bf16x8 af;
          if (idx < F_REG)              af = Areg[idx];
          else if (idx < F_REG + F_LDS) af = *(const bf16x8*)&alw[(idx - F_REG) * 512 + l * 8];
          else {                         // L1-resident global tier; volatile defeats LICM
            const int mt = g * NQ + q;
            u32v4 gw = *(const volatile u32v4*)(wwave + (size_t)(mt * 16) * KDIM + kc * 32);
            af = __builtin_bit_cast(bf16x8, gw);
          }
          acc[g] = __builtin_amdgcn_mfma_f32_16x16x32_bf16(af, bh, acc[g], 0, 0, 0);
        }
      }
      __builtin_amdgcn_s_setprio(0);
      // gates: acc already includes xp
      float hv[4];
#pragma unroll
      for (int j = 0; j < 4; ++j){
        float iv = sigm(acc[0][j]);
        float fv = sigm(acc[1][j]);
        float gv = tanh_f(acc[2][j]);
        float ov = sigm(acc[3][j]);
        float cc = fv * c[q][j] + iv * gv;
        c[q][j] = cc;
        hv[j] = ov * tanh_f(cc);
      }
      if (lb < 8){
        const int u0 = v * (NQ * 16) + q * 16 + lq * 4;
        const int widx = (u0 >> 5) * 512 + ((u0 >> 3) & 3) * 128 + lb * 8 + (u0 & 7);
        uint2 hp; hp.x = cvtpk(hv[0], hv[1]); hp.y = cvtpk(hv[2], hv[3]);
        *(uint2*)&hwr[widx] = hp;
        if (IS_DEC) osv[q] = make_float4(hv[0], hv[1], hv[2], hv[3]);
      }
    }
    __syncthreads();   // h(t) visible; global stores AFTER so vmcnt drain overlaps next step
    if (lb < 8){
#pragma unroll
      for (int q = 0; q < NQ; ++q){
        const int u0 = v * (NQ * 16) + q * 16 + lq * 4;
        if (!IS_DEC){
          const int widx = (u0 >> 5) * 512 + ((u0 >> 3) & 3) * 128 + lb * 8 + (u0 & 7);
          const uint2 hp = *(const uint2*)&hwr[widx];   // re-read (saves hsv regs)
          *(uint2*)(enc_out + (size_t)(t * 256 + b0 + lb) * KDIM + u0) = hp;
        } else {
          *(float4*)(out + ((size_t)(b0 + lb) * T_N + t) * D_N + u0) = osv[q];
        }
      }
    }
    xpl += XSTR_T;
  }
}

extern "C" void kernel_launch(void* const* d_in, const int* in_sizes, int n_in,
                              void* d_out, int out_size, void* d_ws, size_t ws_size,
                              hipStream_t stream){
  const float* x    = (const float*)d_in[0];
  const float* eWih = (const float*)d_in[1];
  const float* eWhh = (const float*)d_in[2];
  const float* ebih = (const float*)d_in[3];
  const float* ebhh = (const float*)d_in[4];
  const float* dWih = (const float*)d_in[5];
  const float* dWhh = (const float*)d_in[6];
  const float* dbih = (const float*)d_in[7];
  const float* dbhh = (const float*)d_in[8];
  float* out = (float*)d_out;

  char* w = (char*)d_ws;
  size_t off = 0;
  auto carve = [&](size_t bytes) -> void* { void* p = w + off; off = (off + bytes + 255) & ~(size_t)255; return p; };
  u16*   xb    = (u16*)carve((size_t)B_N * T_N * D_N * 2);          // x in bf16
  u16*   WihEp = (u16*)carve((size_t)4 * H_N * D_N * 2);            // permuted enc Wih (UB=5,VB=3)
  u16*   WhhEp = (u16*)carve((size_t)4 * H_N * H_N * 2);            // permuted enc Whh (UB=5,VB=3)
  u16*   WihDp = (u16*)carve((size_t)4 * D_N * H_N * 2);            // permuted dec Wih (UB=4,VB=3)
  u16*   WhhDp = (u16*)carve((size_t)4 * D_N * D_N * 2);            // permuted dec Whh (UB=4,VB=3)
  float* bE    = (float*)carve((size_t)4 * H_N * 4);
  float* bD    = (float*)carve((size_t)4 * D_N * 4);
  u16*   xpE   = (u16*)carve((size_t)T_N * B_N * 4 * H_N * 2);      // swizzled [t][wg][v][ch][lq][bl][8]
  u16*   enc   = (u16*)carve((size_t)T_N * B_N * H_N * 2);          // encoded [T][B][H] bf16
  u16*   xpD   = (u16*)carve((size_t)T_N * B_N * 4 * D_N * 2);      // swizzled, dec
  (void)ws_size; (void)in_sizes; (void)n_in; (void)out_size;

  hipLaunchKernelGGL(k_cvt, dim3((B_N * T_N * D_N) / 1024), dim3(256), 0, stream, x, xb, B_N * T_N * D_N);
  hipLaunchKernelGGL(k_permW, dim3(1024), dim3(128), 0, stream, eWih, WihEp, 128, 5, 3);
  hipLaunchKernelGGL(k_permW, dim3(1024), dim3(128), 0, stream, eWhh, WhhEp, 256, 5, 3);
  hipLaunchKernelGGL(k_permW, dim3(512),  dim3(128), 0, stream, dWih, WihDp, 256, 4, 3);
  hipLaunchKernelGGL(k_permW, dim3(512),  dim3(128), 0, stream, dWhh, WhhDp, 128, 4, 3);
  hipLaunchKernelGGL(k_permB, dim3(1), dim3(256), 0, stream, ebih, ebhh, bE, 1024, 5, 3);
  hipLaunchKernelGGL(k_permB, dim3(1), dim3(256), 0, stream, dbih, dbhh, bD, 512, 4, 3);

  // enc x-proj: [65536,1024] = xb @ WihEp^T  (A rows m=b*T+t)
  hipLaunchKernelGGL((k_xproj<128, true, 5, 3>),  dim3(1024, 16), dim3(256), 0, stream, xb,  WihEp, bE, xpE);
  // enc recurrence: 8 waves (2/SIMD), 8 Mtiles x 8 kc, 44 reg + 18 LDS + 2 global frags
  // LDS: 2*8*512*2 + 8*18*1024 = 163840 B (exactly 160 KiB)
  hipLaunchKernelGGL((k_rec<256, 8, 8, 8, 2, 44, 18, false>), dim3(32), dim3(512),
                     2 * 8 * 512 * 2 + 8 * 18 * 1024, stream, WhhEp, xpE, enc, (float*)nullptr);
  // dec x-proj: [65536,512] = enc @ WihDp^T (A rows m=t*B+b)
  hipLaunchKernelGGL((k_xproj<256, false, 4, 3>), dim3(1024, 8),  dim3(256), 0, stream, enc, WihDp, bD, xpD);
  // dec recurrence: 8 waves (2/SIMD), 4 Mtiles x 4 kc, all 16 frags in regs; fp32 out
  // LDS: 2*4*512*2 = 8192 B
  hipLaunchKernelGGL((k_rec<128, 8, 4, 4, 1, 16, 0, true>),  dim3(32), dim3(512),
                     2 * 4 * 512 * 2, stream, WhhDp, xpD, (u16*)nullptr, out);
}

// Round 6
// 1145.061 us; speedup vs baseline: 1.5140x; 1.0847x over previous
//
#include <hip/hip_runtime.h>
#include <stdint.h>

// LSTM autoencoder: B=256,T=256,D=128,H=256, gate order i,f,g,o.
// R1: persistent recurrence, full on-chip weight residency, double-buffered h.
// R2: perm fix for 8-wave dec.
// R3: pre-swizzled xp (coalesced dwordx4 reload in place), cvt_pk.
// R4/R5: enc recurrence 2 waves/SIMD (8 waves, NMT=8, NQ=2); 44 reg + 18 LDS + 2
//     L1-resident global frags; streamed Bh; per-phase xp chunk reload.
// R6: conflict-free frag-order h layout (bank conflicts 4.19M -> 0); acc init from xp;
//     xp reload before MFMA; setprio around MFMA.
// R7: enc phase-merge + DPP lane-packing (gates once on 64 live lanes; Bh reads halved).
// R8 FIX: DPP direction. row_shl:8 (0x108) moves data to LOWER lanes (dest[i]=src[i+8]);
//     dest lanes 8..15 were out-of-row and silently kept 'old' (bound_ctrl=0) -> pack
//     was a no-op, phase-1 computed on zeros (absmax 0.44 ~ sigmoid saturation).
//     Correct ctrl is row_shr:8 (0x118): dest[i]=src[i-8] -> lanes 8..15 <- lanes 0..7
//     (same family rocPRIM scans use to pull from lower lanes).

#define B_N 256
#define T_N 256
#define D_N 128
#define H_N 256

typedef __attribute__((ext_vector_type(8))) short bf16x8;  // MFMA A/B frag (4 VGPRs)
typedef __attribute__((ext_vector_type(4))) float f32x4;   // MFMA C/D frag
typedef unsigned short u16;
typedef unsigned int u32;
typedef __attribute__((ext_vector_type(4))) u32 u32v4;     // builtin vec: volatile-loadable

__device__ __forceinline__ float bflo(u32 u){ return __uint_as_float(u << 16); }
__device__ __forceinline__ float bfhi(u32 u){ return __uint_as_float(u & 0xffff0000u); }
__device__ __forceinline__ u32 f2bf_bits(float f){ u32 u = __float_as_uint(f); return (u + 0x7fffu + ((u >> 16) & 1u)) >> 16; }
__device__ __forceinline__ u32 pack2(float lo, float hi){ return f2bf_bits(lo) | (f2bf_bits(hi) << 16); }
__device__ __forceinline__ u32 cvtpk(float lo, float hi){ u32 r; asm("v_cvt_pk_bf16_f32 %0, %1, %2" : "=v"(r) : "v"(lo), "v"(hi)); return r; }
__device__ __forceinline__ float sigm(float x){ return __builtin_amdgcn_rcpf(1.f + __expf(-x)); }
__device__ __forceinline__ float tanh_f(float x){ return 1.f - 2.f * __builtin_amdgcn_rcpf(1.f + __expf(2.f * x)); }
// lanes lb>=8 <- src lanes lb-8 (row_shr:8, within 16-lane rows); lanes lb<8 keep 'old'
__device__ __forceinline__ float pack_hi(float oldv, float srcv){
  return __uint_as_float((u32)__builtin_amdgcn_update_dpp(
      (int)__float_as_uint(oldv), (int)__float_as_uint(srcv),
      0x118 /*row_shr:8*/, 0xF /*row_mask*/, 0xC /*bank_mask: lanes 8..15*/, false));
}

// ---------- prep kernels ----------
__global__ void k_cvt(const float* __restrict__ src, u16* __restrict__ dst, int n){
  int i = (blockIdx.x * blockDim.x + threadIdx.x) * 4;
  if (i >= n) return;
  float4 v = *(const float4*)(src + i);
  uint2 o; o.x = pack2(v.x, v.y); o.y = pack2(v.z, v.w);
  *(uint2*)(dst + i) = o;
}

// Row permutation p -> orig so that wave v (of 1<<VB waves) owns rows
// [v*4U,(v+1)*4U) = {i,f,g,o} x units[v*U,(v+1)*U), U = 1<<UB units/wave.
// p = (v << (UB+2)) | (g << UB) | uo  ;  orig = (g << (UB+VB)) | (v << UB) | uo
__global__ void k_permW(const float* __restrict__ W, u16* __restrict__ Wp, int K, int UB, int VB){
  int p = blockIdx.x;
  int uo = p & ((1 << UB) - 1), g = (p >> UB) & 3, v = p >> (UB + 2);
  int orig = (g << (UB + VB)) | (v << UB) | uo;
  for (int k = threadIdx.x; k < K; k += blockDim.x)
    Wp[(size_t)p * K + k] = (u16)f2bf_bits(W[(size_t)orig * K + k]);
}

__global__ void k_permB(const float* __restrict__ b1, const float* __restrict__ b2,
                        float* __restrict__ bp, int P, int UB, int VB){
  for (int p = threadIdx.x; p < P; p += blockDim.x){
    int uo = p & ((1 << UB) - 1), g = (p >> UB) & 3, v = p >> (UB + 2);
    int orig = (g << (UB + VB)) | (v << UB) | uo;
    bp[p] = b1[orig] + b2[orig];
  }
}

// ---------- input-projection GEMM: out[m,n] = sum_k A[m,k]*W[n,k] + bias[n] ----------
// Output layout (consumed by k_rec): with n=p -> wv=p>>(UB+2), g=(p>>UB)&3,
// q=(p&mask)>>4, u=p&15, qg=q*4+g, ch=qg>>1, half=qg&1:
// u16 idx = t*TS + (b>>3)*WS + wv*VS + ch*256 + (u>>2)*64 + (b&7)*8 + half*4 + (u&3).
// Phase q of k_rec consumes exactly chunks {2q, 2q+1}.
template<int KTOT, bool ENC_MAP, int UB, int VB>
__global__ __launch_bounds__(256, 1) void k_xproj(const u16* __restrict__ A, const u16* __restrict__ W,
                                                  const float* __restrict__ bias, u16* __restrict__ outp){
  constexpr int NQ  = 1 << (UB - 4);
  constexpr int NCH = 2 * NQ;
  constexpr size_t VS = (size_t)NCH * 256;
  constexpr size_t WS = (size_t)(1 << VB) * VS;
  constexpr size_t TS = 32 * WS;
  __shared__ u16 As[64][72];
  __shared__ u16 Ws[64][72];
  const int tid = threadIdx.x, l = tid & 63, v = tid >> 6;
  const int lb = l & 15, lq = l >> 4;
  const int m0 = blockIdx.x * 64, n0 = blockIdx.y * 64;
  f32x4 acc[4];
#pragma unroll
  for (int nt = 0; nt < 4; nt++){ float bv = bias[n0 + nt * 16 + lb]; f32x4 t = {bv, bv, bv, bv}; acc[nt] = t; }
  const int r = tid >> 3, c8 = (tid & 7) * 8;
  for (int kb = 0; kb < KTOT / 64; ++kb){
    __syncthreads();
    *(bf16x8*)&As[r][c8]      = *(const bf16x8*)&A[(size_t)(m0 + r) * KTOT + kb * 64 + c8];
    *(bf16x8*)&As[r + 32][c8] = *(const bf16x8*)&A[(size_t)(m0 + r + 32) * KTOT + kb * 64 + c8];
    *(bf16x8*)&Ws[r][c8]      = *(const bf16x8*)&W[(size_t)(n0 + r) * KTOT + kb * 64 + c8];
    *(bf16x8*)&Ws[r + 32][c8] = *(const bf16x8*)&W[(size_t)(n0 + r + 32) * KTOT + kb * 64 + c8];
    __syncthreads();
#pragma unroll
    for (int kc = 0; kc < 2; kc++){
      bf16x8 af = *(const bf16x8*)&As[v * 16 + lb][kc * 32 + lq * 8];
#pragma unroll
      for (int nt = 0; nt < 4; nt++){
        bf16x8 wf = *(const bf16x8*)&Ws[nt * 16 + lb][kc * 32 + lq * 8];
        acc[nt] = __builtin_amdgcn_mfma_f32_16x16x32_bf16(af, wf, acc[nt], 0, 0, 0);
      }
    }
  }
#pragma unroll
  for (int nt = 0; nt < 4; nt++){
    const int n  = n0 + nt * 16 + lb;
    const int wv = n >> (UB + 2);
    const int g  = (n >> UB) & 3;
    const int w  = n & ((1 << UB) - 1);
    const int q  = w >> 4;
    const int u  = w & 15;
    const int qg = q * 4 + g;
    const size_t nbase = (size_t)wv * VS + (size_t)(qg >> 1) * 256 + (size_t)(u >> 2) * 64
                       + (size_t)(qg & 1) * 4 + (size_t)(u & 3);
#pragma unroll
    for (int j = 0; j < 4; j += 2){
      const u32 pk = cvtpk(acc[nt][j], acc[nt][j + 1]);
#pragma unroll
      for (int s = 0; s < 2; ++s){
        const int m = m0 + v * 16 + lq * 4 + j + s;
        const int t = ENC_MAP ? (m & 255) : (m >> 8);
        const int b = ENC_MAP ? (m >> 8)  : (m & 255);
        outp[(size_t)t * TS + (size_t)(b >> 3) * WS + (size_t)(b & 7) * 8 + nbase]
            = (u16)(s ? (pk >> 16) : (pk & 0xffffu));
      }
    }
  }
}

// ---------- persistent recurrence ----------
// Grid 32 wgs; wg owns batch slice of 8. Weights = A operand (M = gate rows,
// pre-permuted), h = B operand (N = batch, cols 8..15 dead). Wave v owns rows
// [v*NMT*16, (v+1)*NMT*16). Frag idx = kc*NMT+mt: [0,F_REG) regs, [F_REG,F_REG+F_LDS)
// per-wave LDS, rest volatile-read from global (fixed addr -> L1-hit).
// h double-buffered in LDS in B-FRAGMENT ORDER:
//   u16 idx(b,k) = (k>>5)*512 + ((k>>3)&3)*128 + b*8 + (k&7)
// Bh read per kc = hrd[kc*512 + l*8]: contiguous 1KB, conflict-free. ONE barrier/step.
// NQ==2 (enc): merged phases share each Bh read; DPP-packs phase 1 into lanes lb>=8;
// gates once on 64 live lanes. NQ==1 (dec): per-phase path.
template<int KDIM, int NWAVE, int NMT, int NKC, int NQ, int F_REG, int F_LDS, bool IS_DEC>
__global__ __launch_bounds__(NWAVE * 64, NWAVE / 4) void k_rec(const u16* __restrict__ Wp, const u16* __restrict__ xp,
                                                               u16* __restrict__ enc_out, float* __restrict__ out){
  constexpr int BUFS = NKC * 512;           // u16 per h buffer (frag-order layout)
  constexpr int NCH = 2 * NQ;
  constexpr size_t XSTR_T = (size_t)32 * NWAVE * NCH * 256;   // u16 per timestep
  static_assert(NMT == 4 * NQ, "tiles = 4 gates x NQ unit groups");
  static_assert(F_REG + F_LDS <= NMT * NKC, "reg+LDS tiers within total frags");
  extern __shared__ u16 smem[];
  u16* hbuf = smem;                          // [2][BUFS]
  u16* al   = smem + 2 * BUFS;               // [NWAVE][F_LDS][512]
  const int tid = threadIdx.x, l = tid & 63, v = tid >> 6;
  const int lb = l & 15, lq = l >> 4;
  const int b0 = blockIdx.x * 8;
  const u16* wwave = Wp + (size_t)(v * (NMT * 16) + lb) * KDIM + lq * 8;
  u16* alw = al + (size_t)v * F_LDS * 512;

  // one-time weight load: frag layout A[m=lane&15][k=quad*8+j]
  bf16x8 Areg[(F_REG > 0) ? F_REG : 1];
#pragma unroll
  for (int kc = 0; kc < NKC; ++kc)
#pragma unroll
    for (int mt = 0; mt < NMT; ++mt){
      const int idx = kc * NMT + mt;
      const u16* src = wwave + (size_t)(mt * 16) * KDIM + kc * 32;
      if (idx < F_REG)              Areg[idx] = *(const bf16x8*)src;
      else if (idx < F_REG + F_LDS) *(bf16x8*)&alw[(idx - F_REG) * 512 + l * 8] = *(const bf16x8*)src;
      // idx >= F_REG+F_LDS: stays in global (L1-resident; read per step)
    }

  // xp lane base for this (wg, wave): chunk i at +i*256 u16 (coalesced 512B per chunk)
  const u16* xpl = xp + ((size_t)blockIdx.x * NWAVE + v) * ((size_t)NCH * 256) + lq * 64 + lb * 8;
  uint4 xq[NCH] = {};
  if (lb < 8){
#pragma unroll
    for (int i = 0; i < NCH; ++i) xq[i] = *(const uint4*)(xpl + (size_t)i * 256);
  }

  for (int i = tid; i < 2 * BUFS; i += NWAVE * 64) hbuf[i] = 0;   // h(-1)=0 + dead b-slots
  float c[4];
#pragma unroll
  for (int j = 0; j < 4; j++) c[j] = 0.f;
  __syncthreads();

  for (int t = 0; t < T_N; ++t){
    const u16* hrd = hbuf + (size_t)(t & 1) * BUFS;
    u16*       hwr = hbuf + (size_t)((t & 1) ^ 1) * BUFS;

    if constexpr (NQ == 2){
      // ----- merged 2-phase path (enc) -----
      f32x4 acc[2][4];
#pragma unroll
      for (int ph = 0; ph < 2; ++ph)
#pragma unroll
        for (int g = 0; g < 4; ++g){
          const int qg = ph * 4 + g;
          const uint4 cx = xq[qg >> 1];
          const u32 w0 = (qg & 1) ? cx.z : cx.x;
          const u32 w1 = (qg & 1) ? cx.w : cx.y;
          acc[ph][g][0] = bflo(w0); acc[ph][g][1] = bfhi(w0);
          acc[ph][g][2] = bflo(w1); acc[ph][g][3] = bfhi(w1);
        }
      // reload ALL chunks with t+1 data (full step + barrier of lead)
      if (t + 1 < T_N && lb < 8){
#pragma unroll
        for (int ch = 0; ch < NCH; ++ch)
          xq[ch] = *(const uint4*)(xpl + XSTR_T + (size_t)ch * 256);
      }
      __builtin_amdgcn_s_setprio(1);
#pragma unroll
      for (int kc = 0; kc < NKC; ++kc){
        const bf16x8 bh = *(const bf16x8*)&hrd[kc * 512 + l * 8];  // shared by both phases
#pragma unroll
        for (int ph = 0; ph < 2; ++ph)
#pragma unroll
          for (int g = 0; g < 4; ++g){
            const int idx = kc * NMT + g * NQ + ph;
            bf16x8 af;
            if (idx < F_REG)              af = Areg[idx];
            else if (idx < F_REG + F_LDS) af = *(const bf16x8*)&alw[(idx - F_REG) * 512 + l * 8];
            else {                         // L1-resident global tier; volatile defeats LICM
              const int mt = g * NQ + ph;
              u32v4 gw = *(const volatile u32v4*)(wwave + (size_t)(mt * 16) * KDIM + kc * 32);
              af = __builtin_bit_cast(bf16x8, gw);
            }
            acc[ph][g] = __builtin_amdgcn_mfma_f32_16x16x32_bf16(af, bh, acc[ph][g], 0, 0, 0);
          }
      }
      __builtin_amdgcn_s_setprio(0);
      // pack phase 1 (valid lanes lb<8) into phase 0's dead lanes (lb>=8): 16 DPP movs
      f32x4 comb[4];
#pragma unroll
      for (int g = 0; g < 4; ++g)
#pragma unroll
        for (int j = 0; j < 4; ++j)
          comb[g][j] = pack_hi(acc[0][g][j], acc[1][g][j]);
      // gates once on 64 fully-live lanes: (b = lb&7, phase = lb>>3)
      float hv[4];
#pragma unroll
      for (int j = 0; j < 4; ++j){
        float iv = sigm(comb[0][j]);
        float fv = sigm(comb[1][j]);
        float gv = tanh_f(comb[2][j]);
        float ov = sigm(comb[3][j]);
        float cc = fv * c[j] + iv * gv;
        c[j] = cc;
        hv[j] = ov * tanh_f(cc);
      }
      const int u0 = v * 32 + (lb >> 3) * 16 + lq * 4;
      const int widx = (u0 >> 5) * 512 + ((u0 >> 3) & 3) * 128 + (lb & 7) * 8 + (u0 & 7);
      uint2 hp; hp.x = cvtpk(hv[0], hv[1]); hp.y = cvtpk(hv[2], hv[3]);
      *(uint2*)&hwr[widx] = hp;
      __syncthreads();   // h(t) visible
      {
        const uint2 hs = *(const uint2*)&hwr[widx];
        *(uint2*)(enc_out + (size_t)(t * 256 + b0 + (lb & 7)) * KDIM + u0) = hs;
      }
    } else {
      // ----- single-phase path (dec) -----
      float4 osv[1];
      {
        const int q = 0;
        f32x4 acc[4];
#pragma unroll
        for (int g = 0; g < 4; ++g){
          const uint4 cx = xq[(q * 4 + g) >> 1];
          const u32 w0 = (g & 1) ? cx.z : cx.x;
          const u32 w1 = (g & 1) ? cx.w : cx.y;
          acc[g][0] = bflo(w0); acc[g][1] = bfhi(w0);
          acc[g][2] = bflo(w1); acc[g][3] = bfhi(w1);
        }
        if (t + 1 < T_N && lb < 8){
#pragma unroll
          for (int ch = 0; ch < NCH; ++ch)
            xq[ch] = *(const uint4*)(xpl + XSTR_T + (size_t)ch * 256);
        }
        __builtin_amdgcn_s_setprio(1);
#pragma unroll
        for (int kc = 0; kc < NKC; ++kc){
          const bf16x8 bh = *(const bf16x8*)&hrd[kc * 512 + l * 8];
#pragma unroll
          for (int g = 0; g < 4; ++g){
            const int idx = kc * NMT + g * NQ + q;
            bf16x8 af;
            if (idx < F_REG)              af = Areg[idx];
            else if (idx < F_REG + F_LDS) af = *(const bf16x8*)&alw[(idx - F_REG) * 512 + l * 8];
            else {
              const int mt = g * NQ + q;
              u32v4 gw = *(const volatile u32v4*)(wwave + (size_t)(mt * 16) * KDIM + kc * 32);
              af = __builtin_bit_cast(bf16x8, gw);
            }
            acc[g] = __builtin_amdgcn_mfma_f32_16x16x32_bf16(af, bh, acc[g], 0, 0, 0);
          }
        }
        __builtin_amdgcn_s_setprio(0);
        float hv[4];
#pragma unroll
        for (int j = 0; j < 4; ++j){
          float iv = sigm(acc[0][j]);
          float fv = sigm(acc[1][j]);
          float gv = tanh_f(acc[2][j]);
          float ov = sigm(acc[3][j]);
          float cc = fv * c[j] + iv * gv;
          c[j] = cc;
          hv[j] = ov * tanh_f(cc);
        }
        if (lb < 8){
          const int u0 = v * 16 + lq * 4;
          const int widx = (u0 >> 5) * 512 + ((u0 >> 3) & 3) * 128 + lb * 8 + (u0 & 7);
          uint2 hp; hp.x = cvtpk(hv[0], hv[1]); hp.y = cvtpk(hv[2], hv[3]);
          *(uint2*)&hwr[widx] = hp;
          osv[0] = make_float4(hv[0], hv[1], hv[2], hv[3]);
        }
      }
      __syncthreads();
      if (lb < 8){
        const int u0 = v * 16 + lq * 4;
        *(float4*)(out + ((size_t)(b0 + lb) * T_N + t) * D_N + u0) = osv[0];
      }
    }
    xpl += XSTR_T;
  }
}

extern "C" void kernel_launch(void* const* d_in, const int* in_sizes, int n_in,
                              void* d_out, int out_size, void* d_ws, size_t ws_size,
                              hipStream_t stream){
  const float* x    = (const float*)d_in[0];
  const float* eWih = (const float*)d_in[1];
  const float* eWhh = (const float*)d_in[2];
  const float* ebih = (const float*)d_in[3];
  const float* ebhh = (const float*)d_in[4];
  const float* dWih = (const float*)d_in[5];
  const float* dWhh = (const float*)d_in[6];
  const float* dbih = (const float*)d_in[7];
  const float* dbhh = (const float*)d_in[8];
  float* out = (float*)d_out;

  char* w = (char*)d_ws;
  size_t off = 0;
  auto carve = [&](size_t bytes) -> void* { void* p = w + off; off = (off + bytes + 255) & ~(size_t)255; return p; };
  u16*   xb    = (u16*)carve((size_t)B_N * T_N * D_N * 2);          // x in bf16
  u16*   WihEp = (u16*)carve((size_t)4 * H_N * D_N * 2);            // permuted enc Wih (UB=5,VB=3)
  u16*   WhhEp = (u16*)carve((size_t)4 * H_N * H_N * 2);            // permuted enc Whh (UB=5,VB=3)
  u16*   WihDp = (u16*)carve((size_t)4 * D_N * H_N * 2);            // permuted dec Wih (UB=4,VB=3)
  u16*   WhhDp = (u16*)carve((size_t)4 * D_N * D_N * 2);            // permuted dec Whh (UB=4,VB=3)
  float* bE    = (float*)carve((size_t)4 * H_N * 4);
  float* bD    = (float*)carve((size_t)4 * D_N * 4);
  u16*   xpE   = (u16*)carve((size_t)T_N * B_N * 4 * H_N * 2);      // swizzled [t][wg][v][ch][lq][bl][8]
  u16*   enc   = (u16*)carve((size_t)T_N * B_N * H_N * 2);          // encoded [T][B][H] bf16
  u16*   xpD   = (u16*)carve((size_t)T_N * B_N * 4 * D_N * 2);      // swizzled, dec
  (void)ws_size; (void)in_sizes; (void)n_in; (void)out_size;

  hipLaunchKernelGGL(k_cvt, dim3((B_N * T_N * D_N) / 1024), dim3(256), 0, stream, x, xb, B_N * T_N * D_N);
  hipLaunchKernelGGL(k_permW, dim3(1024), dim3(128), 0, stream, eWih, WihEp, 128, 5, 3);
  hipLaunchKernelGGL(k_permW, dim3(1024), dim3(128), 0, stream, eWhh, WhhEp, 256, 5, 3);
  hipLaunchKernelGGL(k_permW, dim3(512),  dim3(128), 0, stream, dWih, WihDp, 256, 4, 3);
  hipLaunchKernelGGL(k_permW, dim3(512),  dim3(128), 0, stream, dWhh, WhhDp, 128, 4, 3);
  hipLaunchKernelGGL(k_permB, dim3(1), dim3(256), 0, stream, ebih, ebhh, bE, 1024, 5, 3);
  hipLaunchKernelGGL(k_permB, dim3(1), dim3(256), 0, stream, dbih, dbhh, bD, 512, 4, 3);

  // enc x-proj: [65536,1024] = xb @ WihEp^T  (A rows m=b*T+t)
  hipLaunchKernelGGL((k_xproj<128, true, 5, 3>),  dim3(1024, 16), dim3(256), 0, stream, xb,  WihEp, bE, xpE);
  // enc recurrence: 8 waves (2/SIMD), 8 Mtiles x 8 kc, 44 reg + 18 LDS + 2 global frags
  // LDS: 2*8*512*2 + 8*18*1024 = 163840 B (exactly 160 KiB)
  hipLaunchKernelGGL((k_rec<256, 8, 8, 8, 2, 44, 18, false>), dim3(32), dim3(512),
                     2 * 8 * 512 * 2 + 8 * 18 * 1024, stream, WhhEp, xpE, enc, (float*)nullptr);
  // dec x-proj: [65536,512] = enc @ WihDp^T (A rows m=t*B+b)
  hipLaunchKernelGGL((k_xproj<256, false, 4, 3>), dim3(1024, 8),  dim3(256), 0, stream, enc, WihDp, bD, xpD);
  // dec recurrence: 8 waves (2/SIMD), 4 Mtiles x 4 kc, all 16 frags in regs; fp32 out
  // LDS: 2*4*512*2 = 8192 B
  hipLaunchKernelGGL((k_rec<128, 8, 4, 4, 1, 16, 0, true>),  dim3(32), dim3(512),
                     2 * 4 * 512 * 2, stream, WhhDp, xpD, (u16*)nullptr, out);
}